// Round 4
// baseline (981.195 us; speedup 1.0000x reference)
//
#include <hip/hip_runtime.h>

#define NN 50000
#define DD 128
#define HH 3
#define LL 2
#define EE 500000
#define WE 36          // ELL width (Poisson(10): P(deg>36) ~ 3e-11)
#define HP2 136        // padded LDS row for bf16 tiles (2-way conflicts only)
#define FPAD 132       // padded LDS row (floats) for epilogue transpose

using short8v = __attribute__((ext_vector_type(8))) short;
using short4v = __attribute__((ext_vector_type(4))) short;
using f32x4   = __attribute__((ext_vector_type(4))) float;

__device__ __forceinline__ ushort f2bf_rne(float x) {
    union { float f; uint u; } c; c.f = x;
    uint u = c.u;
    uint r = (u + 0x7FFFu + ((u >> 16) & 1u)) >> 16;
    return (ushort)r;
}
__device__ __forceinline__ float bf2f(ushort h) {
    union { uint u; float f; } c; c.u = ((uint)h) << 16;
    return c.f;
}
__device__ __forceinline__ short8v load_frag(const ushort* p) {
    short4v a0 = *(const short4v*)(p);
    short4v a1 = *(const short4v*)(p + 16);
    return __builtin_shufflevector(a0, a1, 0, 1, 2, 3, 4, 5, 6, 7);
}

// ---------------- weight prep: split fp32 W[k][n] -> bf16 WThi[n][k], WTlo[n][k] ----------------
__global__ void prep_w_kernel(const float* __restrict__ w1, const float* __restrict__ w2,
                              ushort* __restrict__ wsplit) {
    int t = blockIdx.x * blockDim.x + threadIdx.x;
    if (t >= 12 * 16384) return;
    int mi = t >> 14;
    int r  = t & 16383;
    int nn = r >> 7;
    int kk = r & 127;
    const float* W = (mi < 6) ? (w1 + (size_t)mi * 16384) : (w2 + (size_t)(mi - 6) * 16384);
    float v = W[kk * 128 + nn];
    ushort hi = f2bf_rne(v);
    float lo = v - bf2f(hi);
    ushort* base = wsplit + (size_t)mi * 32768;
    base[nn * 128 + kk]         = hi;
    base[16384 + nn * 128 + kk] = f2bf_rne(lo);
}

// ---------------- ELL build ----------------
__global__ void fill_ell_kernel(const int* __restrict__ src, const int* __restrict__ dst,
                                int* __restrict__ cnt, ushort* __restrict__ ell) {
    int e = blockIdx.x * blockDim.x + threadIdx.x;
    if (e >= EE) return;
    int d = dst[e];
    int p = atomicAdd(&cnt[d], 1);
    if (p < WE) ell[(size_t)d * WE + p] = (ushort)src[e];
}

// ---------------- fused layer: out = (1+eps)*x + sum_hop relu((x+agg)@W1)@W2 ----------------
// 512 threads = 8 waves, 64 rows per block.
__global__ __launch_bounds__(512, 1)
void layer_kernel(const float* __restrict__ x,
                  const ushort* __restrict__ wsplit,   // 12 matrices, [hi|lo], WT layout [n][k]
                  const int* __restrict__ counts,      // [H][N]
                  const ushort* __restrict__ ell,      // [H][N][WE]
                  const float* __restrict__ eps,
                  float* __restrict__ out, int n, int layer) {
    __shared__ ushort sH[2 * 64 * HP2];     // hi | lo regions (34816 B); aliased as float for epilogue
    ushort* sHhi = sH;
    ushort* sHlo = sH + 64 * HP2;

    const int tid  = threadIdx.x;
    const int lane = tid & 63;
    const int wid  = tid >> 6;
    const int l15  = lane & 15;
    const int lg   = lane >> 4;
    const int rh   = wid & 1;
    const int cs   = wid >> 1;
    const int row0 = blockIdx.x * 64;

    f32x4 accO[2][2];
    #pragma unroll
    for (int rt = 0; rt < 2; ++rt)
        #pragma unroll
        for (int ct = 0; ct < 2; ++ct)
            accO[rt][ct] = (f32x4){0.f, 0.f, 0.f, 0.f};

    const float2* xp = (const float2*)x;

    for (int hop = 0; hop < HH; ++hop) {
        const ushort* W1p = wsplit + (size_t)(layer * HH + hop) * 32768;
        const ushort* W2p = wsplit + (size_t)(6 + layer * HH + hop) * 32768;
        const int* cnt = counts + (size_t)hop * NN;
        const ushort* el0 = ell + (size_t)hop * NN * WE;

        // ---- gather: wave wid handles rows wid*8 .. wid*8+7; lane holds elems 2*lane, 2*lane+1 ----
        #pragma unroll
        for (int rr = 0; rr < 8; ++rr) {
            const int rl = wid * 8 + rr;
            const int node = row0 + rl;
            float2 a0 = make_float2(0.f, 0.f);
            if (node < n) {
                int c = cnt[node];
                if (c > WE) c = WE;
                const ushort* el = el0 + (size_t)node * WE;
                a0 = xp[(size_t)node * 64 + lane];
                float2 a1 = make_float2(0.f, 0.f);
                float2 a2 = make_float2(0.f, 0.f);
                float2 a3 = make_float2(0.f, 0.f);
                int i = 0;
                for (; i + 4 <= c; i += 4) {
                    int s0 = el[i], s1 = el[i + 1], s2 = el[i + 2], s3 = el[i + 3];
                    float2 v0 = xp[(size_t)s0 * 64 + lane];
                    float2 v1 = xp[(size_t)s1 * 64 + lane];
                    float2 v2 = xp[(size_t)s2 * 64 + lane];
                    float2 v3 = xp[(size_t)s3 * 64 + lane];
                    a0.x += v0.x; a0.y += v0.y;
                    a1.x += v1.x; a1.y += v1.y;
                    a2.x += v2.x; a2.y += v2.y;
                    a3.x += v3.x; a3.y += v3.y;
                }
                for (; i < c; ++i) {
                    int s0 = el[i];
                    float2 v0 = xp[(size_t)s0 * 64 + lane];
                    a0.x += v0.x; a0.y += v0.y;
                }
                a0.x += a1.x + a2.x + a3.x;
                a0.y += a1.y + a2.y + a3.y;
            }
            // split + pack into LDS (ushort2 as uint; 2-way bank aliasing = free)
            ushort hx = f2bf_rne(a0.x);
            ushort hy = f2bf_rne(a0.y);
            uint hp = (uint)hx | ((uint)hy << 16);
            float lx = a0.x - bf2f(hx);
            float ly = a0.y - bf2f(hy);
            uint lp = (uint)f2bf_rne(lx) | ((uint)f2bf_rne(ly) << 16);
            *(uint*)(&sHhi[rl * HP2 + 2 * lane]) = hp;
            *(uint*)(&sHlo[rl * HP2 + 2 * lane]) = lp;
        }
        __syncthreads();

        // ---- GEMM1: t = h @ W1 ----
        f32x4 acc[2][2];
        #pragma unroll
        for (int rt = 0; rt < 2; ++rt)
            #pragma unroll
            for (int ct = 0; ct < 2; ++ct)
                acc[rt][ct] = (f32x4){0.f, 0.f, 0.f, 0.f};

        #pragma unroll
        for (int ks = 0; ks < 4; ++ks) {
            const int kb = ks * 32 + lg * 4;
            short8v Ah[2], Al[2];
            #pragma unroll
            for (int rt = 0; rt < 2; ++rt) {
                const int m = rh * 32 + rt * 16 + l15;
                Ah[rt] = load_frag(&sHhi[m * HP2 + kb]);
                Al[rt] = load_frag(&sHlo[m * HP2 + kb]);
            }
            short8v Bh[2], Bl[2];
            #pragma unroll
            for (int ct = 0; ct < 2; ++ct) {
                const int wrow = cs * 32 + ct * 16 + l15;
                Bh[ct] = load_frag(W1p + wrow * 128 + kb);
                Bl[ct] = load_frag(W1p + 16384 + wrow * 128 + kb);
            }
            #pragma unroll
            for (int rt = 0; rt < 2; ++rt) {
                #pragma unroll
                for (int ct = 0; ct < 2; ++ct) {
                    acc[rt][ct] = __builtin_amdgcn_mfma_f32_16x16x32_bf16(Ah[rt], Bh[ct], acc[rt][ct], 0, 0, 0);
                    acc[rt][ct] = __builtin_amdgcn_mfma_f32_16x16x32_bf16(Ah[rt], Bl[ct], acc[rt][ct], 0, 0, 0);
                    acc[rt][ct] = __builtin_amdgcn_mfma_f32_16x16x32_bf16(Al[rt], Bh[ct], acc[rt][ct], 0, 0, 0);
                }
            }
        }
        __syncthreads();   // all GEMM1 LDS reads done

        // ---- relu + split, write T into LDS ----
        #pragma unroll
        for (int rt = 0; rt < 2; ++rt) {
            #pragma unroll
            for (int ct = 0; ct < 2; ++ct) {
                const int col = cs * 32 + ct * 16 + l15;
                #pragma unroll
                for (int r = 0; r < 4; ++r) {
                    const int row = rh * 32 + rt * 16 + lg * 4 + r;
                    float v = fmaxf(acc[rt][ct][r], 0.f);
                    ushort hh = f2bf_rne(v);
                    sHhi[row * HP2 + col] = hh;
                    sHlo[row * HP2 + col] = f2bf_rne(v - bf2f(hh));
                }
            }
        }
        __syncthreads();

        // ---- GEMM2: accO += T @ W2 ----
        #pragma unroll
        for (int ks = 0; ks < 4; ++ks) {
            const int kb = ks * 32 + lg * 4;
            short8v Ah[2], Al[2];
            #pragma unroll
            for (int rt = 0; rt < 2; ++rt) {
                const int m = rh * 32 + rt * 16 + l15;
                Ah[rt] = load_frag(&sHhi[m * HP2 + kb]);
                Al[rt] = load_frag(&sHlo[m * HP2 + kb]);
            }
            short8v Bh[2], Bl[2];
            #pragma unroll
            for (int ct = 0; ct < 2; ++ct) {
                const int wrow = cs * 32 + ct * 16 + l15;
                Bh[ct] = load_frag(W2p + wrow * 128 + kb);
                Bl[ct] = load_frag(W2p + 16384 + wrow * 128 + kb);
            }
            #pragma unroll
            for (int rt = 0; rt < 2; ++rt) {
                #pragma unroll
                for (int ct = 0; ct < 2; ++ct) {
                    accO[rt][ct] = __builtin_amdgcn_mfma_f32_16x16x32_bf16(Ah[rt], Bh[ct], accO[rt][ct], 0, 0, 0);
                    accO[rt][ct] = __builtin_amdgcn_mfma_f32_16x16x32_bf16(Ah[rt], Bl[ct], accO[rt][ct], 0, 0, 0);
                    accO[rt][ct] = __builtin_amdgcn_mfma_f32_16x16x32_bf16(Al[rt], Bh[ct], accO[rt][ct], 0, 0, 0);
                }
            }
        }
        __syncthreads();   // protect LDS before next hop's gather writes
    }

    // ---- epilogue: transpose accO through LDS, out = (1+eps)*x + accO (coalesced, write-only) ----
    float* fepi = (float*)sH;   // [64][FPAD] floats = 33792 B <= 34816 B
    #pragma unroll
    for (int rt = 0; rt < 2; ++rt) {
        #pragma unroll
        for (int ct = 0; ct < 2; ++ct) {
            const int col = cs * 32 + ct * 16 + l15;
            #pragma unroll
            for (int r = 0; r < 4; ++r) {
                const int row = rh * 32 + rt * 16 + lg * 4 + r;
                fepi[row * FPAD + col] = accO[rt][ct][r];
            }
        }
    }
    __syncthreads();

    const float s = 1.0f + eps[0];
    const int c4 = tid & 31;     // float4 column group
    const int r4 = tid >> 5;     // 0..15
    #pragma unroll
    for (int i = 0; i < 4; ++i) {
        const int rl = r4 + i * 16;
        const int gr = row0 + rl;
        if (gr < n) {
            float4 a = *(const float4*)(&fepi[rl * FPAD + c4 * 4]);
            const float4 xv = *(const float4*)(x + (size_t)gr * DD + c4 * 4);
            a.x += s * xv.x;
            a.y += s * xv.y;
            a.z += s * xv.z;
            a.w += s * xv.w;
            *(float4*)(out + (size_t)gr * DD + c4 * 4) = a;
        }
    }
}

extern "C" void kernel_launch(void* const* d_in, const int* in_sizes, int n_in,
                              void* d_out, int out_size, void* d_ws, size_t ws_size,
                              hipStream_t stream) {
    const float* x    = (const float*)d_in[0];
    const float* w1   = (const float*)d_in[1];
    const float* w2   = (const float*)d_in[2];
    const float* eps  = (const float*)d_in[3];
    const int*   sidx = (const int*)d_in[4];
    const int*   nidx = (const int*)d_in[5];
    float* out = (float*)d_out;

    // workspace layout
    float*  xbuf   = (float*)d_ws;                           // [N][D] layer-0 output
    ushort* wsplit = (ushort*)(xbuf + (size_t)NN * DD);      // 12 * 32768 bf16
    int*    counts = (int*)(wsplit + 12 * 32768);            // [H][N]
    ushort* ell    = (ushort*)(counts + HH * NN);            // [H][N][WE]

    hipMemsetAsync(counts, 0, (size_t)HH * NN * sizeof(int), stream);
    prep_w_kernel<<<(12 * 16384 + 255) / 256, 256, 0, stream>>>(w1, w2, wsplit);
    for (int hop = 0; hop < HH; ++hop) {
        fill_ell_kernel<<<(EE + 255) / 256, 256, 0, stream>>>(
            sidx + (size_t)hop * EE, nidx + (size_t)hop * EE,
            counts + (size_t)hop * NN, ell + (size_t)hop * NN * WE);
    }

    const int nblk = (NN + 63) / 64;
    layer_kernel<<<nblk, 512, 0, stream>>>(x,    wsplit, counts, ell, eps, xbuf, NN, 0);
    layer_kernel<<<nblk, 512, 0, stream>>>(xbuf, wsplit, counts, ell, eps, out,  NN, 1);
}

// Round 5
// 461.030 us; speedup vs baseline: 2.1283x; 2.1283x over previous
//
#include <hip/hip_runtime.h>

#define NN 50000
#define DD 128
#define HH 3
#define LL 2
#define EE 500000
#define WE 36          // ELL width (in-degree ~ Poisson(10); P(deg>36) negligible)
#define HP2 136        // padded LDS row (ushorts) for h/T tiles
#define FPAD 132       // padded LDS row (floats) for epilogue transpose

using short8v  = __attribute__((ext_vector_type(8))) short;
using short4v  = __attribute__((ext_vector_type(4))) short;
using ushort4v = __attribute__((ext_vector_type(4))) ushort;
using f32x4    = __attribute__((ext_vector_type(4))) float;

__device__ __forceinline__ ushort f2bf_rne(float x) {
    union { float f; uint u; } c; c.f = x;
    uint u = c.u;
    uint r = (u + 0x7FFFu + ((u >> 16) & 1u)) >> 16;
    return (ushort)r;
}
__device__ __forceinline__ float blo(uint v) { union { uint u; float f; } c; c.u = v << 16; return c.f; }
__device__ __forceinline__ float bhi(uint v) { union { uint u; float f; } c; c.u = v & 0xFFFF0000u; return c.f; }
__device__ __forceinline__ uint packbf(float a, float b) {
    return (uint)f2bf_rne(a) | ((uint)f2bf_rne(b) << 16);
}
// MFMA fragment: k-slots {kb..kb+3, kb+16..kb+19} — HW-nominal layout, proven in R3/R4
__device__ __forceinline__ short8v load_frag(const ushort* p) {
    short4v a0 = *(const short4v*)(p);
    short4v a1 = *(const short4v*)(p + 16);
    return __builtin_shufflevector(a0, a1, 0, 1, 2, 3, 4, 5, 6, 7);
}

// ---------------- prep: xbf = bf16(x), packed 2/uint ----------------
__global__ void prep_x_kernel(const float* __restrict__ x, uint* __restrict__ xbf) {
    int i = blockIdx.x * blockDim.x + threadIdx.x;
    if (i >= NN * DD / 4) return;
    float4 v = ((const float4*)x)[i];
    uint2 p;
    p.x = packbf(v.x, v.y);
    p.y = packbf(v.z, v.w);
    ((uint2*)xbf)[i] = p;
}

// ---------------- prep: wbf[mi][n][k] = bf16(W_mi[k][n]) (transposed) ----------------
__global__ void prep_w_kernel(const float* __restrict__ w1, const float* __restrict__ w2,
                              ushort* __restrict__ wbf) {
    int t = blockIdx.x * blockDim.x + threadIdx.x;
    if (t >= 12 * 16384) return;
    int mi = t >> 14;
    int r  = t & 16383;
    int nn = r >> 7;
    int kk = r & 127;
    const float* W = (mi < 6) ? (w1 + (size_t)mi * 16384) : (w2 + (size_t)(mi - 6) * 16384);
    wbf[(size_t)mi * 16384 + nn * 128 + kk] = f2bf_rne(W[kk * 128 + nn]);
}

// ---------------- ELL build, all 3 hops in one dispatch ----------------
__global__ void fill_ell_kernel(const int* __restrict__ src, const int* __restrict__ dst,
                                int* __restrict__ cnt, ushort* __restrict__ ell) {
    int e = blockIdx.x * blockDim.x + threadIdx.x;
    if (e >= HH * EE) return;
    int hop = e / EE;
    int d = dst[e];
    int p = atomicAdd(&cnt[hop * NN + d], 1);
    if (p < WE) ell[((size_t)hop * NN + d) * WE + p] = (ushort)src[e];
}

// ---------------- gather: hbuf[hop][d] = bf16( x[d] + sum_nbrs x[s] ) ----------------
// one wave per (hop, node); lane holds 2 bf16 elems (1 uint)
__global__ __launch_bounds__(256)
void gather_kernel(const uint* __restrict__ xbf, const int* __restrict__ counts,
                   const ushort* __restrict__ ell, uint* __restrict__ hbuf, int n) {
    const int node = blockIdx.x * 4 + (threadIdx.x >> 6);
    const int hop  = blockIdx.y;
    const int lane = threadIdx.x & 63;
    if (node >= n) return;
    int c = counts[hop * NN + node];
    if (c > WE) c = WE;
    const ushort* el = ell + ((size_t)hop * NN + node) * WE;
    uint sv = xbf[(size_t)node * 64 + lane];     // include_self
    float ax = blo(sv), ay = bhi(sv);
    float bx = 0.f, by = 0.f, cx = 0.f, cy = 0.f, dx = 0.f, dy = 0.f;
    int i = 0;
    for (; i + 4 <= c; i += 4) {
        ushort4v s4 = *(const ushort4v*)(el + i);
        uint v0 = xbf[(size_t)s4[0] * 64 + lane];
        uint v1 = xbf[(size_t)s4[1] * 64 + lane];
        uint v2 = xbf[(size_t)s4[2] * 64 + lane];
        uint v3 = xbf[(size_t)s4[3] * 64 + lane];
        ax += blo(v0); ay += bhi(v0);
        bx += blo(v1); by += bhi(v1);
        cx += blo(v2); cy += bhi(v2);
        dx += blo(v3); dy += bhi(v3);
    }
    for (; i < c; ++i) {
        uint v = xbf[(size_t)el[i] * 64 + lane];
        ax += blo(v); ay += bhi(v);
    }
    ax += bx + cx + dx;
    ay += by + cy + dy;
    hbuf[((size_t)hop * NN + node) * 64 + lane] = packbf(ax, ay);
}

// ---------------- MLP over all 3 hops: acc = sum_hop relu(h_hop@W1)@W2; out = (1+eps)x + acc ----------------
// 512 threads = 8 waves; 64-row tile. Wave: rows rh*32+rt*16, cols cs*32+ct*16.
__global__ __launch_bounds__(512)
void mlp3_kernel(const ushort* __restrict__ hbuf, const uint* __restrict__ xbf_in,
                 const ushort* __restrict__ wbf, const float* __restrict__ eps,
                 float* __restrict__ outf, uint* __restrict__ outbf, int n, int layer) {
    __shared__ __align__(16) char smem[64 * FPAD * 4];   // 33792 B
    ushort* sA   = (ushort*)smem;    // [64][HP2] bf16 tile (h, then T)
    float*  fepi = (float*)smem;     // [64][FPAD] epilogue transpose

    const int tid  = threadIdx.x;
    const int lane = tid & 63;
    const int wid  = tid >> 6;
    const int l15  = lane & 15;
    const int lg   = lane >> 4;
    const int rh   = wid & 1;
    const int cs   = wid >> 1;
    const int row0 = blockIdx.x * 64;

    f32x4 accO[2][2];
    #pragma unroll
    for (int rt = 0; rt < 2; ++rt)
        #pragma unroll
        for (int ct = 0; ct < 2; ++ct)
            accO[rt][ct] = (f32x4){0.f, 0.f, 0.f, 0.f};

    for (int hop = 0; hop < HH; ++hop) {
        const ushort* W1p = wbf + (size_t)(layer * HH + hop) * 16384;
        const ushort* W2p = wbf + (size_t)(6 + layer * HH + hop) * 16384;

        // ---- stage h tile: 64 rows x 128 bf16 (1024 x 16B chunks) ----
        #pragma unroll
        for (int it = 0; it < 2; ++it) {
            int idx = tid + it * 512;
            int r  = idx >> 4;
            int cc = idx & 15;
            int gr = row0 + r;
            uint4 v = make_uint4(0u, 0u, 0u, 0u);
            if (gr < n) v = *(const uint4*)(hbuf + ((size_t)hop * NN + gr) * DD + cc * 8);
            *(uint4*)(&sA[r * HP2 + cc * 8]) = v;
        }
        __syncthreads();

        // ---- GEMM1: t = h @ W1 ----
        f32x4 acc[2][2];
        #pragma unroll
        for (int rt = 0; rt < 2; ++rt)
            #pragma unroll
            for (int ct = 0; ct < 2; ++ct)
                acc[rt][ct] = (f32x4){0.f, 0.f, 0.f, 0.f};

        #pragma unroll
        for (int ks = 0; ks < 4; ++ks) {
            const int kb = ks * 32 + lg * 4;
            short8v A0 = load_frag(&sA[(rh * 32 + 0 + l15) * HP2 + kb]);
            short8v A1 = load_frag(&sA[(rh * 32 + 16 + l15) * HP2 + kb]);
            short8v B0 = load_frag(W1p + (cs * 32 + 0 + l15) * 128 + kb);
            short8v B1 = load_frag(W1p + (cs * 32 + 16 + l15) * 128 + kb);
            acc[0][0] = __builtin_amdgcn_mfma_f32_16x16x32_bf16(A0, B0, acc[0][0], 0, 0, 0);
            acc[0][1] = __builtin_amdgcn_mfma_f32_16x16x32_bf16(A0, B1, acc[0][1], 0, 0, 0);
            acc[1][0] = __builtin_amdgcn_mfma_f32_16x16x32_bf16(A1, B0, acc[1][0], 0, 0, 0);
            acc[1][1] = __builtin_amdgcn_mfma_f32_16x16x32_bf16(A1, B1, acc[1][1], 0, 0, 0);
        }
        __syncthreads();

        // ---- T = bf16(relu(t)) into sA ----
        #pragma unroll
        for (int rt = 0; rt < 2; ++rt) {
            #pragma unroll
            for (int ct = 0; ct < 2; ++ct) {
                const int col = cs * 32 + ct * 16 + l15;
                #pragma unroll
                for (int r = 0; r < 4; ++r) {
                    const int row = rh * 32 + rt * 16 + lg * 4 + r;
                    sA[row * HP2 + col] = f2bf_rne(fmaxf(acc[rt][ct][r], 0.f));
                }
            }
        }
        __syncthreads();

        // ---- GEMM2: accO += T @ W2 ----
        #pragma unroll
        for (int ks = 0; ks < 4; ++ks) {
            const int kb = ks * 32 + lg * 4;
            short8v A0 = load_frag(&sA[(rh * 32 + 0 + l15) * HP2 + kb]);
            short8v A1 = load_frag(&sA[(rh * 32 + 16 + l15) * HP2 + kb]);
            short8v B0 = load_frag(W2p + (cs * 32 + 0 + l15) * 128 + kb);
            short8v B1 = load_frag(W2p + (cs * 32 + 16 + l15) * 128 + kb);
            accO[0][0] = __builtin_amdgcn_mfma_f32_16x16x32_bf16(A0, B0, accO[0][0], 0, 0, 0);
            accO[0][1] = __builtin_amdgcn_mfma_f32_16x16x32_bf16(A0, B1, accO[0][1], 0, 0, 0);
            accO[1][0] = __builtin_amdgcn_mfma_f32_16x16x32_bf16(A1, B0, accO[1][0], 0, 0, 0);
            accO[1][1] = __builtin_amdgcn_mfma_f32_16x16x32_bf16(A1, B1, accO[1][1], 0, 0, 0);
        }
        __syncthreads();   // protect sA before next hop's staging
    }

    // ---- epilogue: transpose accO; out = (1+eps)*x + accO, write-only ----
    #pragma unroll
    for (int rt = 0; rt < 2; ++rt) {
        #pragma unroll
        for (int ct = 0; ct < 2; ++ct) {
            const int col = cs * 32 + ct * 16 + l15;
            #pragma unroll
            for (int r = 0; r < 4; ++r) {
                const int row = rh * 32 + rt * 16 + lg * 4 + r;
                fepi[row * FPAD + col] = accO[rt][ct][r];
            }
        }
    }
    __syncthreads();

    const float s = 1.0f + eps[0];
    #pragma unroll
    for (int it = 0; it < 4; ++it) {
        int idx = tid + it * 512;
        int r  = idx >> 5;       // 32 float4-chunks per row
        int cc = idx & 31;
        int gr = row0 + r;
        if (gr < n) {
            float4 a = *(const float4*)(&fepi[r * FPAD + cc * 4]);
            uint2 xv = *(const uint2*)(xbf_in + (size_t)gr * 64 + cc * 2);
            a.x += s * blo(xv.x);
            a.y += s * bhi(xv.x);
            a.z += s * blo(xv.y);
            a.w += s * bhi(xv.y);
            if (outf != nullptr) {
                *(float4*)(outf + (size_t)gr * DD + cc * 4) = a;
            } else {
                uint2 p;
                p.x = packbf(a.x, a.y);
                p.y = packbf(a.z, a.w);
                *(uint2*)(outbf + (size_t)gr * 64 + cc * 2) = p;
            }
        }
    }
}

extern "C" void kernel_launch(void* const* d_in, const int* in_sizes, int n_in,
                              void* d_out, int out_size, void* d_ws, size_t ws_size,
                              hipStream_t stream) {
    const float* x    = (const float*)d_in[0];
    const float* w1   = (const float*)d_in[1];
    const float* w2   = (const float*)d_in[2];
    const float* eps  = (const float*)d_in[3];
    const int*   sidx = (const int*)d_in[4];
    const int*   nidx = (const int*)d_in[5];
    float* out = (float*)d_out;

    // workspace layout (~63 MB)
    uint*   xbf    = (uint*)d_ws;                          // [N][64] packed bf16 x
    uint*   hbuf   = xbf + (size_t)NN * 64;                // [H][N][64] packed bf16 h
    ushort* wbf    = (ushort*)(hbuf + (size_t)HH * NN * 64);  // [12][128][128] bf16 W^T
    ushort* ell    = wbf + 12 * 16384;                     // [H][N][WE]
    int*    counts = (int*)(ell + (size_t)HH * NN * WE);   // [H][N]

    hipMemsetAsync(counts, 0, (size_t)HH * NN * sizeof(int), stream);
    prep_x_kernel<<<(NN * DD / 4 + 255) / 256, 256, 0, stream>>>(x, xbf);
    prep_w_kernel<<<(12 * 16384 + 255) / 256, 256, 0, stream>>>(w1, w2, wbf);
    fill_ell_kernel<<<(HH * EE + 255) / 256, 256, 0, stream>>>(sidx, nidx, counts, ell);

    dim3 ggrid((NN + 3) / 4, HH);
    const int mblk = (NN + 63) / 64;

    // layer 0: consumes xbf, produces new xbf (bf16 only)
    gather_kernel<<<ggrid, 256, 0, stream>>>(xbf, counts, ell, hbuf, NN);
    mlp3_kernel<<<mblk, 512, 0, stream>>>((const ushort*)hbuf, xbf, wbf, eps,
                                          nullptr, xbf, NN, 0);
    // layer 1: consumes xbf, produces fp32 out
    gather_kernel<<<ggrid, 256, 0, stream>>>(xbf, counts, ell, hbuf, NN);
    mlp3_kernel<<<mblk, 512, 0, stream>>>((const ushort*)hbuf, xbf, wbf, eps,
                                          out, nullptr, NN, 1);
}